// Round 4
// baseline (242.020 us; speedup 1.0000x reference)
//
#include <hip/hip_runtime.h>
#include <math.h>

#define D_MODEL 512
#define STATE_DIM 16
#define MASK_BUCKETS 2048
#define PPB 256        // points per block (divides N=65536 -> one batch b per block)
#define CHUNK 64       // points staged per LDS chunk
#define NCHUNK (PPB / CHUNK)

typedef float v4f __attribute__((ext_vector_type(4)));

__device__ __forceinline__ v4f f4_load(const float* p) { return *(const v4f*)p; }
__device__ __forceinline__ v4f f4_fma(float s, v4f a, v4f b) {
    return (v4f){fmaf(s, a.x, b.x), fmaf(s, a.y, b.y), fmaf(s, a.z, b.z), fmaf(s, a.w, b.w)};
}

// Each block: 256 threads, 256 points, one batch index b.
// Thread layout: d = (tid&127)*4 -> float4 slice of D=512; sub = tid>>7 -> point parity.
// Per-point scalars staged in LDS (computed once), double-buffered across 64-pt chunks.
__global__ __launch_bounds__(256) void point_proj_kernel(
    const float* __restrict__ xyz,
    const float* __restrict__ state,
    const float* __restrict__ rgb,
    const int*   __restrict__ mask_id,
    const float* __restrict__ Wxyz,
    const float* __restrict__ Wrgb,
    const float* __restrict__ rgb_alpha,
    const float* __restrict__ Wg,
    const float* __restrict__ gripper_alpha,
    const float* __restrict__ mask_embed,
    float* __restrict__ out,
    int n_points)  // N per batch
{
    __shared__ v4f sA[2][CHUNK];  // {x, y, z, dist}
    __shared__ v4f sB[2][CHUNK];  // {r0, r1, r2, bitcast(masked m)}

    const int tid = threadIdx.x;
    const int d   = (tid & 127) << 2;
    const int sub = tid >> 7;

    const float ra = rgb_alpha[0];
    const float ga = gripper_alpha[0];

    const long long p0 = (long long)blockIdx.x * PPB;
    const int b = (int)(p0 / n_points);

    const float gx = state[b * STATE_DIM + 0];
    const float gy = state[b * STATE_DIM + 1];
    const float gz = state[b * STATE_DIM + 2];

    // ---- fold weights into registers (once per thread) ----
    v4f G0 = f4_load(&Wg[0 * D_MODEL + d]) * ga;
    v4f G1 = f4_load(&Wg[1 * D_MODEL + d]) * ga;
    v4f G2 = f4_load(&Wg[2 * D_MODEL + d]) * ga;
    v4f G3 = f4_load(&Wg[3 * D_MODEL + d]) * ga;
    v4f Cb = -(G0 * gx + G1 * gy + G2 * gz);     // -ga*(gxyz . Wg[0:3])
    v4f A0 = f4_load(&Wxyz[0 * D_MODEL + d]) + G0;
    v4f A1 = f4_load(&Wxyz[1 * D_MODEL + d]) + G1;
    v4f A2 = f4_load(&Wxyz[2 * D_MODEL + d]) + G2;
    v4f R0 = f4_load(&Wrgb[0 * D_MODEL + d]) * ra;
    v4f R1 = f4_load(&Wrgb[1 * D_MODEL + d]) * ra;
    v4f R2 = f4_load(&Wrgb[2 * D_MODEL + d]) * ra;

    // staging registers (threads 0..63 only)
    float lx = 0.f, ly = 0.f, lz = 0.f, lr0 = 0.f, lr1 = 0.f, lr2 = 0.f;
    int lm = 0;

    // issue chunk-0 staged loads (NT: streamed once, don't pollute L2)
    if (tid < CHUNK) {
        long long gp = p0 + tid;
        lx  = __builtin_nontemporal_load(&xyz[gp * 3 + 0]);
        ly  = __builtin_nontemporal_load(&xyz[gp * 3 + 1]);
        lz  = __builtin_nontemporal_load(&xyz[gp * 3 + 2]);
        lr0 = __builtin_nontemporal_load(&rgb[gp * 3 + 0]);
        lr1 = __builtin_nontemporal_load(&rgb[gp * 3 + 1]);
        lr2 = __builtin_nontemporal_load(&rgb[gp * 3 + 2]);
        lm  = __builtin_nontemporal_load(&mask_id[gp]);
        const float rx = lx - gx, ry = ly - gy, rz = lz - gz;
        const float dist = sqrtf(rx * rx + ry * ry + rz * rz);
        sA[0][tid] = (v4f){lx, ly, lz, dist};
        sB[0][tid] = (v4f){lr0, lr1, lr2, __int_as_float(lm & (MASK_BUCKETS - 1))};
    }
    __syncthreads();

    for (int c = 0; c < NCHUNK; ++c) {
        const int cur = c & 1;
        const bool has_next = (c + 1 < NCHUNK);

        // issue next chunk's global loads early — latency hides under inner loop
        if (has_next && tid < CHUNK) {
            long long gp = p0 + (long long)(c + 1) * CHUNK + tid;
            lx  = __builtin_nontemporal_load(&xyz[gp * 3 + 0]);
            ly  = __builtin_nontemporal_load(&xyz[gp * 3 + 1]);
            lz  = __builtin_nontemporal_load(&xyz[gp * 3 + 2]);
            lr0 = __builtin_nontemporal_load(&rgb[gp * 3 + 0]);
            lr1 = __builtin_nontemporal_load(&rgb[gp * 3 + 1]);
            lr2 = __builtin_nontemporal_load(&rgb[gp * 3 + 2]);
            lm  = __builtin_nontemporal_load(&mask_id[gp]);
        }

        // inner loop: 4 points per iteration (sub split x hand-unroll 2)
        const long long cbase = p0 + (long long)c * CHUNK;
        for (int i = 0; i < CHUNK; i += 4) {
            const int q0 = i + sub;
            const int q1 = i + 2 + sub;

            // broadcast LDS reads (same addr across wave -> conflict-free)
            const v4f a0 = sA[cur][q0], b0 = sB[cur][q0];
            const v4f a1 = sA[cur][q1], b1 = sB[cur][q1];
            const int m0 = __float_as_int(b0.w);
            const int m1 = __float_as_int(b1.w);

            // two gathers in flight (regular loads: keep table L2-resident)
            const v4f me0 = f4_load(&mask_embed[(size_t)m0 * D_MODEL + d]);
            const v4f me1 = f4_load(&mask_embed[(size_t)m1 * D_MODEL + d]);

            v4f o0 = Cb + me0;
            o0 = f4_fma(a0.x, A0, o0);
            o0 = f4_fma(a0.y, A1, o0);
            o0 = f4_fma(a0.z, A2, o0);
            o0 = f4_fma(b0.x, R0, o0);
            o0 = f4_fma(b0.y, R1, o0);
            o0 = f4_fma(b0.z, R2, o0);
            o0 = f4_fma(a0.w, G3, o0);

            v4f o1 = Cb + me1;
            o1 = f4_fma(a1.x, A0, o1);
            o1 = f4_fma(a1.y, A1, o1);
            o1 = f4_fma(a1.z, A2, o1);
            o1 = f4_fma(b1.x, R0, o1);
            o1 = f4_fma(b1.y, R1, o1);
            o1 = f4_fma(b1.z, R2, o1);
            o1 = f4_fma(a1.w, G3, o1);

            __builtin_nontemporal_store(o0, (v4f*)&out[(size_t)(cbase + q0) * D_MODEL + d]);
            __builtin_nontemporal_store(o1, (v4f*)&out[(size_t)(cbase + q1) * D_MODEL + d]);
        }

        // finish staging next chunk into the other buffer
        if (has_next && tid < CHUNK) {
            const float rx = lx - gx, ry = ly - gy, rz = lz - gz;
            const float dist = sqrtf(rx * rx + ry * ry + rz * rz);
            sA[cur ^ 1][tid] = (v4f){lx, ly, lz, dist};
            sB[cur ^ 1][tid] = (v4f){lr0, lr1, lr2, __int_as_float(lm & (MASK_BUCKETS - 1))};
        }
        __syncthreads();
    }
}

// state token: st = silu(state @ Ws1 + bs1) @ Ws2 + bs2, B blocks of 512 thr
__global__ __launch_bounds__(512) void state_token_kernel(
    const float* __restrict__ state,
    const float* __restrict__ Ws1,
    const float* __restrict__ bs1,
    const float* __restrict__ Ws2,
    const float* __restrict__ bs2,
    float* __restrict__ out)  // already offset to state_token base
{
    __shared__ float u[D_MODEL];
    const int b = blockIdx.x;
    const int d = threadIdx.x;

    float acc = bs1[d];
#pragma unroll
    for (int k = 0; k < STATE_DIM; ++k)
        acc = fmaf(state[b * STATE_DIM + k], Ws1[k * D_MODEL + d], acc);
    u[d] = acc / (1.0f + expf(-acc));  // silu
    __syncthreads();

    float acc2 = bs2[d];
#pragma unroll 8
    for (int k = 0; k < D_MODEL; ++k)
        acc2 = fmaf(u[k], Ws2[k * D_MODEL + d], acc2);

    out[(size_t)b * D_MODEL + d] = acc2;
}

extern "C" void kernel_launch(void* const* d_in, const int* in_sizes, int n_in,
                              void* d_out, int out_size, void* d_ws, size_t ws_size,
                              hipStream_t stream) {
    const float* xyz           = (const float*)d_in[0];
    const float* state         = (const float*)d_in[1];
    const float* rgb           = (const float*)d_in[2];
    const int*   mask_id       = (const int*)  d_in[3];
    const float* Wxyz          = (const float*)d_in[4];
    const float* Wrgb          = (const float*)d_in[5];
    const float* rgb_alpha     = (const float*)d_in[6];
    const float* Wg            = (const float*)d_in[7];
    const float* gripper_alpha = (const float*)d_in[8];
    const float* Ws1           = (const float*)d_in[9];
    const float* bs1           = (const float*)d_in[10];
    const float* Ws2           = (const float*)d_in[11];
    const float* bs2           = (const float*)d_in[12];
    const float* mask_embed    = (const float*)d_in[13];
    float* out = (float*)d_out;

    const int B = in_sizes[1] / STATE_DIM;              // 8
    const long long total_points = in_sizes[3];         // B*N = 524288
    const int N = (int)(total_points / B);              // 65536

    const int grid = (int)(total_points / PPB);         // 2048 blocks

    point_proj_kernel<<<grid, 256, 0, stream>>>(
        xyz, state, rgb, mask_id, Wxyz, Wrgb, rgb_alpha, Wg, gripper_alpha,
        mask_embed, out, N);

    state_token_kernel<<<B, D_MODEL, 0, stream>>>(
        state, Ws1, bs1, Ws2, bs2,
        out + (size_t)total_points * D_MODEL);
}

// Round 5
// 224.958 us; speedup vs baseline: 1.0758x; 1.0758x over previous
//
#include <hip/hip_runtime.h>
#include <math.h>

#define D_MODEL 512
#define STATE_DIM 16
#define MASK_BUCKETS 2048
#define PPB 256              // points per block; divides N=65536 -> one batch per block
#define N_STATE_BLOCKS 16    // 8 batches x 2 halves of D

typedef float v4f __attribute__((ext_vector_type(4)));

__device__ __forceinline__ v4f f4_load(const float* p) { return *(const v4f*)p; }
__device__ __forceinline__ v4f f4_fma(float s, v4f a, v4f b) {
    return (v4f){fmaf(s, a.x, b.x), fmaf(s, a.y, b.y), fmaf(s, a.z, b.z), fmaf(s, a.w, b.w)};
}

// Fused kernel. Blocks [0, N_STATE_BLOCKS) compute the state token (tiny,
// overlaps with the big point blocks instead of serializing after them).
// Blocks [N_STATE_BLOCKS, ...) each process PPB contiguous points of one batch.
__global__ __launch_bounds__(256) void fused_proj_kernel(
    const float* __restrict__ xyz,
    const float* __restrict__ state,
    const float* __restrict__ rgb,
    const int*   __restrict__ mask_id,
    const float* __restrict__ Wxyz,
    const float* __restrict__ Wrgb,
    const float* __restrict__ rgb_alpha,
    const float* __restrict__ Wg,
    const float* __restrict__ gripper_alpha,
    const float* __restrict__ Ws1,
    const float* __restrict__ bs1,
    const float* __restrict__ Ws2,
    const float* __restrict__ bs2,
    const float* __restrict__ mask_embed,
    float* __restrict__ out,
    long long total_points,
    int n_points)  // N per batch
{
    const int tid = threadIdx.x;

    if (blockIdx.x < N_STATE_BLOCKS) {
        // ---------------- state token path ----------------
        // block = (batch b, half of D). 256 threads.
        __shared__ float u[D_MODEL];
        const int b    = blockIdx.x >> 1;
        const int half = blockIdx.x & 1;

        // phase 1: hidden = silu(state @ Ws1 + bs1); each thread 2 dims
        #pragma unroll
        for (int r = 0; r < 2; ++r) {
            const int j = tid + r * 256;
            float acc = bs1[j];
            #pragma unroll
            for (int k = 0; k < STATE_DIM; ++k)
                acc = fmaf(state[b * STATE_DIM + k], Ws1[k * D_MODEL + j], acc);
            u[j] = acc / (1.0f + expf(-acc));   // x * sigmoid(x)
        }
        __syncthreads();

        // phase 2: out col c = bs2[c] + sum_k u[k] * Ws2[k, c]
        const int c = half * 256 + tid;
        float acc2 = bs2[c];
        #pragma unroll 8
        for (int k = 0; k < D_MODEL; ++k)
            acc2 = fmaf(u[k], Ws2[k * D_MODEL + c], acc2);

        out[(size_t)total_points * D_MODEL + (size_t)b * D_MODEL + c] = acc2;
        return;
    }

    // ---------------- point path (R2 structure + 2x unroll) ----------------
    const int d   = (tid & 127) << 2;   // float4 column slice of D=512
    const int sub = tid >> 7;           // point parity within an iter-pair

    const float ra = rgb_alpha[0];
    const float ga = gripper_alpha[0];

    const long long p0 = (long long)(blockIdx.x - N_STATE_BLOCKS) * PPB;
    const int b = (int)(p0 / n_points);

    const float gx = state[b * STATE_DIM + 0];
    const float gy = state[b * STATE_DIM + 1];
    const float gz = state[b * STATE_DIM + 2];

    // fold weights into registers (once per thread)
    v4f G0 = f4_load(&Wg[0 * D_MODEL + d]) * ga;
    v4f G1 = f4_load(&Wg[1 * D_MODEL + d]) * ga;
    v4f G2 = f4_load(&Wg[2 * D_MODEL + d]) * ga;
    v4f G3 = f4_load(&Wg[3 * D_MODEL + d]) * ga;
    v4f Cb = -(G0 * gx + G1 * gy + G2 * gz);       // -ga*(gxyz . Wg[0:3])
    v4f A0 = f4_load(&Wxyz[0 * D_MODEL + d]) + G0;
    v4f A1 = f4_load(&Wxyz[1 * D_MODEL + d]) + G1;
    v4f A2 = f4_load(&Wxyz[2 * D_MODEL + d]) + G2;
    v4f R0 = f4_load(&Wrgb[0 * D_MODEL + d]) * ra;
    v4f R1 = f4_load(&Wrgb[1 * D_MODEL + d]) * ra;
    v4f R2 = f4_load(&Wrgb[2 * D_MODEL + d]) * ra;

    const int iters = PPB / 4;   // 2 points per thread per iter
    for (int i = 0; i < iters; ++i) {
        const long long pa = p0 + (long long)(i << 2) + sub;
        const long long pb = pa + 2;

        // per-point scalars: broadcast loads (same addr across wave, L1-served)
        const float xa = xyz[pa * 3 + 0], ya = xyz[pa * 3 + 1], za = xyz[pa * 3 + 2];
        const float xb = xyz[pb * 3 + 0], yb = xyz[pb * 3 + 1], zb = xyz[pb * 3 + 2];
        const float ra0 = rgb[pa * 3 + 0], ra1 = rgb[pa * 3 + 1], ra2 = rgb[pa * 3 + 2];
        const float rb0 = rgb[pb * 3 + 0], rb1 = rgb[pb * 3 + 1], rb2 = rgb[pb * 3 + 2];
        const int ma = mask_id[pa] & (MASK_BUCKETS - 1);
        const int mb = mask_id[pb] & (MASK_BUCKETS - 1);

        // two gathers in flight (plain loads: keep 4MB table L2-resident)
        const v4f mea = f4_load(&mask_embed[(size_t)ma * D_MODEL + d]);
        const v4f meb = f4_load(&mask_embed[(size_t)mb * D_MODEL + d]);

        const float rxa = xa - gx, rya = ya - gy, rza = za - gz;
        const float rxb = xb - gx, ryb = yb - gy, rzb = zb - gz;
        const float da = sqrtf(rxa * rxa + rya * rya + rza * rza);
        const float db = sqrtf(rxb * rxb + ryb * ryb + rzb * rzb);

        v4f oa = Cb + mea;
        oa = f4_fma(xa,  A0, oa);
        oa = f4_fma(ya,  A1, oa);
        oa = f4_fma(za,  A2, oa);
        oa = f4_fma(ra0, R0, oa);
        oa = f4_fma(ra1, R1, oa);
        oa = f4_fma(ra2, R2, oa);
        oa = f4_fma(da,  G3, oa);

        v4f ob = Cb + meb;
        ob = f4_fma(xb,  A0, ob);
        ob = f4_fma(yb,  A1, ob);
        ob = f4_fma(zb,  A2, ob);
        ob = f4_fma(rb0, R0, ob);
        ob = f4_fma(rb1, R1, ob);
        ob = f4_fma(rb2, R2, ob);
        ob = f4_fma(db,  G3, ob);

        // nontemporal: 1GB write stream must not evict the mask table from L2
        __builtin_nontemporal_store(oa, (v4f*)&out[(size_t)pa * D_MODEL + d]);
        __builtin_nontemporal_store(ob, (v4f*)&out[(size_t)pb * D_MODEL + d]);
    }
}

extern "C" void kernel_launch(void* const* d_in, const int* in_sizes, int n_in,
                              void* d_out, int out_size, void* d_ws, size_t ws_size,
                              hipStream_t stream) {
    const float* xyz           = (const float*)d_in[0];
    const float* state         = (const float*)d_in[1];
    const float* rgb           = (const float*)d_in[2];
    const int*   mask_id       = (const int*)  d_in[3];
    const float* Wxyz          = (const float*)d_in[4];
    const float* Wrgb          = (const float*)d_in[5];
    const float* rgb_alpha     = (const float*)d_in[6];
    const float* Wg            = (const float*)d_in[7];
    const float* gripper_alpha = (const float*)d_in[8];
    const float* Ws1           = (const float*)d_in[9];
    const float* bs1           = (const float*)d_in[10];
    const float* Ws2           = (const float*)d_in[11];
    const float* bs2           = (const float*)d_in[12];
    const float* mask_embed    = (const float*)d_in[13];
    float* out = (float*)d_out;

    const int B = in_sizes[1] / STATE_DIM;              // 8
    const long long total_points = in_sizes[3];         // B*N = 524288
    const int N = (int)(total_points / B);              // 65536

    const int grid = N_STATE_BLOCKS + (int)(total_points / PPB);  // 16 + 2048

    fused_proj_kernel<<<grid, 256, 0, stream>>>(
        xyz, state, rgb, mask_id, Wxyz, Wrgb, rgb_alpha, Wg, gripper_alpha,
        Ws1, bs1, Ws2, bs2, mask_embed, out, total_points, N);
}